// Round 21
// baseline (76.378 us; speedup 1.0000x reference)
//
#include <hip/hip_runtime.h>
#include <math.h>

#define RED_BLOCKS 256
#define NT 512             // k_h threads
#define AT 1024            // k_accum threads (16 waves, 1 block/CU)
#define CCH 19968          // nodes per chunk
#define CPAD (CCH + 64)    // +64 per-lane dummy slots; 2*CPAD*4 = 160256 B LDS
#define ORD_OFF 0x007fffffu  // f2ord(-inf); shifted so 0 == "-inf"/empty

// Monotone order-preserving float->uint mapping, shifted so 0 means -inf.
__device__ __forceinline__ unsigned f2ord(float f) {
    unsigned u = __float_as_uint(f);
    u = (u & 0x80000000u) ? ~u : (u | 0x80000000u);
    return u - ORD_OFF;
}
__device__ __forceinline__ float ord2f(unsigned uo) {
    unsigned u = uo + ORD_OFF;
    unsigned v = (u & 0x80000000u) ? (u & 0x7fffffffu) : ~u;
    return __uint_as_float(v);
}

__device__ __forceinline__ void h_row_body(const float* __restrict__ loss,
                                           const float* __restrict__ Ws,
                                           float* __restrict__ h,
                                           unsigned* __restrict__ ordArr,
                                           int n, int blk) {
    int sub = threadIdx.x & 15, r = threadIdx.x >> 4;   // 32 rows per 512-thread block
    int row = blk * (NT / 16) + r;
    if (row >= n) return;
    const float4* f4 = (const float4*)(loss + (size_t)row * 200);
    const float4* W4 = (const float4*)Ws;
    float4 a, w;
    float acc = 0.0f;
    a = f4[sub];      w = W4[sub];      acc += a.x*w.x + a.y*w.y + a.z*w.z + a.w*w.w;
    a = f4[sub + 16]; w = W4[sub + 16]; acc += a.x*w.x + a.y*w.y + a.z*w.z + a.w*w.w;
    a = f4[sub + 32]; w = W4[sub + 32]; acc += a.x*w.x + a.y*w.y + a.z*w.z + a.w*w.w;
    if (sub < 2) { a = f4[48 + sub]; w = W4[48 + sub]; acc += a.x*w.x + a.y*w.y + a.z*w.z + a.w*w.w; }
    #pragma unroll
    for (int off = 8; off > 0; off >>= 1) acc += __shfl_down(acc, off, 16);
    if (sub == 0) { h[row] = acc; ordArr[row] = f2ord(acc); }
}

__global__ void __launch_bounds__(NT) k_h(const float* __restrict__ loss,
                                          const float* __restrict__ Ws,
                                          float* __restrict__ h,
                                          unsigned* __restrict__ ordArr, int n) {
    h_row_body(loss, Ws, h, ordArr, n, blockIdx.x);
}

// Scatter-free segment-max, BRANCHLESS inner loop. r20 diagnosis: masked
// gathers `(cond)?ordArr[x]:0` compile to exec-mask branches per element,
// serializing the 32 gathers/pack (VALUBusy 18%, VGPR 52). Fix:
//  - gather with cndmask'd ADDRESS (masked lanes read ordArr[0]; same-address
//    lanes coalesce to 1 segment -> TA cost ~= active lanes),
//  - LDS atomicMax with cndmask'd INDEX into 64 per-lane dummy words
//    (write-only garbage, bank-spread, never stored out).
// Zero branches -> all 32 gathers pipelined in flight. Exact, order-free ->
// bit-deterministic.
__global__ void __launch_bounds__(AT, 4) k_accum(
        const int* __restrict__ src, const int* __restrict__ dst,
        const unsigned* __restrict__ ordArr, unsigned* __restrict__ partials,
        int ne, int nch, int split, int epb) {
    __shared__ unsigned preL[CPAD];
    __shared__ unsigned sucL[CPAD];
    int c = blockIdx.x / split, sub = blockIdx.x - c * split;
    for (int t = threadIdx.x; t < CPAD; t += AT) { preL[t] = 0u; sucL[t] = 0u; }
    __syncthreads();
    const unsigned clo = (unsigned)c * CCH;
    const unsigned lane = threadIdx.x & 63;
    const unsigned dummy = CCH + lane;
    int lo = sub * epb, hi = min(sub * epb + epb, ne);

    int i = lo + (int)threadIdx.x * 16;
    for (; i + 15 < hi; i += AT * 16) {
        // phase 1: 8 independent edge int4 loads
        int4 s0 = *(const int4*)(src + i);
        int4 s1 = *(const int4*)(src + i + 4);
        int4 s2 = *(const int4*)(src + i + 8);
        int4 s3 = *(const int4*)(src + i + 12);
        int4 d0 = *(const int4*)(dst + i);
        int4 d1 = *(const int4*)(dst + i + 4);
        int4 d2 = *(const int4*)(dst + i + 8);
        int4 d3 = *(const int4*)(dst + i + 12);
        int ss[16] = { s0.x, s0.y, s0.z, s0.w, s1.x, s1.y, s1.z, s1.w,
                       s2.x, s2.y, s2.z, s2.w, s3.x, s3.y, s3.z, s3.w };
        int dd[16] = { d0.x, d0.y, d0.z, d0.w, d1.x, d1.y, d1.z, d1.w,
                       d2.x, d2.y, d2.z, d2.w, d3.x, d3.y, d3.z, d3.w };
        // phase 2: branchless address select + unconditional gathers
        unsigned dl[16], sl[16], gp[16], gs[16];
        #pragma unroll
        for (int u = 0; u < 16; ++u) {
            bool same = (ss[u] == dd[u]);
            dl[u] = same ? ~0u : (unsigned)dd[u] - clo;
            sl[u] = same ? ~0u : (unsigned)ss[u] - clo;
            unsigned gaP = (dl[u] < CCH) ? (unsigned)ss[u] : 0u;
            unsigned gaS = (sl[u] < CCH) ? (unsigned)dd[u] : 0u;
            gp[u] = ordArr[gaP];
            gs[u] = ordArr[gaS];
        }
        // phase 3: branchless index select + unconditional LDS atomics
        #pragma unroll
        for (int u = 0; u < 16; ++u) {
            unsigned ip = (dl[u] < CCH) ? dl[u] : dummy;
            unsigned is2 = (sl[u] < CCH) ? sl[u] : dummy;
            unsigned vp = (dl[u] < CCH) ? gp[u] : 0u;
            unsigned vs = (sl[u] < CCH) ? gs[u] : 0u;
            atomicMax(&preL[ip], vp);
            atomicMax(&sucL[is2], vs);
        }
    }
    for (int j = i; j < hi; ++j) {   // tail
        if (j >= lo) {
            int s = src[j], d = dst[j];
            bool same = (s == d);
            unsigned dl = same ? ~0u : (unsigned)d - clo;
            unsigned sl = same ? ~0u : (unsigned)s - clo;
            unsigned gaP = (dl < CCH) ? (unsigned)s : 0u;
            unsigned gaS = (sl < CCH) ? (unsigned)d : 0u;
            unsigned vp = (dl < CCH) ? ordArr[gaP] : 0u;
            unsigned vs = (sl < CCH) ? ordArr[gaS] : 0u;
            atomicMax(&preL[(dl < CCH) ? dl : dummy], vp);
            atomicMax(&sucL[(sl < CCH) ? sl : dummy], vs);
        }
    }
    __syncthreads();
    size_t pb = ((size_t)c * split + sub) * CCH;
    size_t sucOff = (size_t)nch * split * CCH;
    for (int t = threadIdx.x; t < CCH; t += AT) {
        partials[pb + t] = preL[t];
        partials[sucOff + pb + t] = sucL[t];
    }
}

// Fused fold+logit+exp with BLOCK-LOCAL max; logits in named scalars.
__global__ void __launch_bounds__(256) k_fold_exp(
        const float* __restrict__ h, const unsigned* __restrict__ partials,
        const float* __restrict__ Wg, float* __restrict__ out,
        float* __restrict__ maxPart, float* __restrict__ sumPart,
        int n, int nch, int split) {
    __shared__ float sm[256];
    float w0 = Wg[0], w1 = Wg[1];
    size_t sucOff = (size_t)nch * split * CCH;
    const int NTH = 256 * RED_BLOCKS;
    int i0 = blockIdx.x * 256 + threadIdx.x;
    int i1 = i0 + NTH;                         // n <= 2*65536 for this path

    float l0 = -INFINITY, l1 = -INFINITY;
    if (i0 < n) {
        int c = i0 / CCH, loc = i0 - c * CCH;
        const unsigned* pp = partials + ((size_t)c * split) * CCH + loc;
        const unsigned* sp = pp + sucOff;
        unsigned p = 0, s = 0;
        #pragma unroll 4
        for (int k = 0; k < split; ++k) {
            p = max(p, pp[(size_t)k * CCH]);
            s = max(s, sp[(size_t)k * CCH]);
        }
        l0 = h[i0] + w0 * (p ? ord2f(p) : 0.0f) + w1 * (s ? ord2f(s) : 0.0f);
    }
    if (i1 < n) {
        int c = i1 / CCH, loc = i1 - c * CCH;
        const unsigned* pp = partials + ((size_t)c * split) * CCH + loc;
        const unsigned* sp = pp + sucOff;
        unsigned p = 0, s = 0;
        #pragma unroll 4
        for (int k = 0; k < split; ++k) {
            p = max(p, pp[(size_t)k * CCH]);
            s = max(s, sp[(size_t)k * CCH]);
        }
        l1 = h[i1] + w0 * (p ? ord2f(p) : 0.0f) + w1 * (s ? ord2f(s) : 0.0f);
    }
    sm[threadIdx.x] = fmaxf(l0, l1);
    __syncthreads();
    for (int off = 128; off > 0; off >>= 1) {
        if (threadIdx.x < off) sm[threadIdx.x] = fmaxf(sm[threadIdx.x], sm[threadIdx.x + off]);
        __syncthreads();
    }
    float mb = sm[0];
    __syncthreads();
    float e0 = 0.0f, e1 = 0.0f;
    if (i0 < n) { e0 = expf(l0 - mb); out[i0] = e0; }
    if (i1 < n) { e1 = expf(l1 - mb); out[i1] = e1; }
    sm[threadIdx.x] = e0 + e1;
    __syncthreads();
    for (int off = 128; off > 0; off >>= 1) {
        if (threadIdx.x < off) sm[threadIdx.x] += sm[threadIdx.x + off];
        __syncthreads();
    }
    if (threadIdx.x == 0) { maxPart[blockIdx.x] = mb; sumPart[blockIdx.x] = sm[0]; }
}

// Every block redundantly (deterministically) computes gmax + rescaled sum,
// then rescales its own elements: out[i] *= exp(m_b - gmax) / S.
__global__ void __launch_bounds__(256) k_norm2(
        const float* __restrict__ maxPart, const float* __restrict__ sumPart,
        float* __restrict__ out, int n) {
    __shared__ float sm[256];
    const int NTH = 256 * RED_BLOCKS;
    sm[threadIdx.x] = maxPart[threadIdx.x];
    __syncthreads();
    for (int off = 128; off > 0; off >>= 1) {
        if (threadIdx.x < off) sm[threadIdx.x] = fmaxf(sm[threadIdx.x], sm[threadIdx.x + off]);
        __syncthreads();
    }
    float gmax = sm[0];
    __syncthreads();
    sm[threadIdx.x] = sumPart[threadIdx.x] * expf(maxPart[threadIdx.x] - gmax);
    __syncthreads();
    for (int off = 128; off > 0; off >>= 1) {
        if (threadIdx.x < off) sm[threadIdx.x] += sm[threadIdx.x + off];
        __syncthreads();
    }
    float scale = expf(maxPart[blockIdx.x] - gmax) / sm[0];
    int i0 = blockIdx.x * 256 + threadIdx.x;
    int i1 = i0 + NTH;
    if (i0 < n) out[i0] *= scale;
    if (i1 < n) out[i1] *= scale;
}

// ---- Fallback path (any n) ----
__global__ void k_edges_dev(const int* __restrict__ src, const int* __restrict__ dst,
                            const float* __restrict__ h, unsigned* __restrict__ partials, int ne) {
    int e = blockIdx.x * blockDim.x + threadIdx.x;
    if (e >= ne) return;
    int s = src[e], d = dst[e];
    if (s == d) return;
    unsigned hs = f2ord(h[s]);
    unsigned hd = f2ord(h[d]);
    unsigned* slot0 = &partials[d];
    unsigned* slot1 = &partials[(1 << 17) + s];
    if (*slot0 < hs) atomicMax(slot0, hs);
    if (*slot1 < hd) atomicMax(slot1, hd);
}

__global__ void k_logit_max(const float* __restrict__ h, const unsigned* __restrict__ partials,
                            const float* __restrict__ Wg, float* __restrict__ logit,
                            float* __restrict__ maxPart, int n, int nch, int split) {
    __shared__ float sm[256];
    float w0 = Wg[0], w1 = Wg[1];
    size_t sucOff = (size_t)nch * split * CCH;
    float m = -INFINITY;
    for (int i = blockIdx.x * 256 + threadIdx.x; i < n; i += 256 * RED_BLOCKS) {
        int c = i / CCH, loc = i - c * CCH;
        const unsigned* pp = partials + ((size_t)c * split) * CCH + loc;
        const unsigned* sp = pp + sucOff;
        unsigned p = 0, s = 0;
        #pragma unroll 4
        for (int k = 0; k < split; ++k) {
            p = max(p, pp[(size_t)k * CCH]);
            s = max(s, sp[(size_t)k * CCH]);
        }
        float pf = p ? ord2f(p) : 0.0f;
        float sf = s ? ord2f(s) : 0.0f;
        float l = h[i] + w0 * pf + w1 * sf;
        logit[i] = l;
        m = fmaxf(m, l);
    }
    sm[threadIdx.x] = m;
    __syncthreads();
    for (int off = 128; off > 0; off >>= 1) {
        if (threadIdx.x < off) sm[threadIdx.x] = fmaxf(sm[threadIdx.x], sm[threadIdx.x + off]);
        __syncthreads();
    }
    if (threadIdx.x == 0) maxPart[blockIdx.x] = sm[0];
}

__global__ void k_logit_max_dev(const float* __restrict__ h, const unsigned* __restrict__ partials,
                                const float* __restrict__ Wg, float* __restrict__ logit,
                                float* __restrict__ maxPart, int n) {
    __shared__ float sm[256];
    float w0 = Wg[0], w1 = Wg[1];
    float m = -INFINITY;
    for (int i = blockIdx.x * 256 + threadIdx.x; i < n; i += 256 * RED_BLOCKS) {
        unsigned p = partials[i], s = partials[(1 << 17) + i];
        float pf = p ? ord2f(p) : 0.0f;
        float sf = s ? ord2f(s) : 0.0f;
        float l = h[i] + w0 * pf + w1 * sf;
        logit[i] = l;
        m = fmaxf(m, l);
    }
    sm[threadIdx.x] = m;
    __syncthreads();
    for (int off = 128; off > 0; off >>= 1) {
        if (threadIdx.x < off) sm[threadIdx.x] = fmaxf(sm[threadIdx.x], sm[threadIdx.x + off]);
        __syncthreads();
    }
    if (threadIdx.x == 0) maxPart[blockIdx.x] = sm[0];
}

__global__ void k_exp_sum(const float* __restrict__ logit, const float* __restrict__ maxPart,
                          float* __restrict__ out, float* __restrict__ sumPart, int n) {
    __shared__ float sm[256];
    sm[threadIdx.x] = maxPart[threadIdx.x];
    __syncthreads();
    for (int off = 128; off > 0; off >>= 1) {
        if (threadIdx.x < off) sm[threadIdx.x] = fmaxf(sm[threadIdx.x], sm[threadIdx.x + off]);
        __syncthreads();
    }
    float gmax = sm[0];
    __syncthreads();
    float acc = 0.0f;
    for (int i = blockIdx.x * 256 + threadIdx.x; i < n; i += 256 * RED_BLOCKS) {
        float e = expf(logit[i] - gmax);
        out[i] = e;
        acc += e;
    }
    sm[threadIdx.x] = acc;
    __syncthreads();
    for (int off = 128; off > 0; off >>= 1) {
        if (threadIdx.x < off) sm[threadIdx.x] += sm[threadIdx.x + off];
        __syncthreads();
    }
    if (threadIdx.x == 0) sumPart[blockIdx.x] = sm[0];
}

__global__ void k_norm(const float* __restrict__ sumPart, float* __restrict__ out, int n) {
    __shared__ float sm[256];
    sm[threadIdx.x] = sumPart[threadIdx.x];
    __syncthreads();
    for (int off = 128; off > 0; off >>= 1) {
        if (threadIdx.x < off) sm[threadIdx.x] += sm[threadIdx.x + off];
        __syncthreads();
    }
    float inv = 1.0f / sm[0];
    for (int i = blockIdx.x * 256 + threadIdx.x; i < n; i += 256 * RED_BLOCKS) out[i] *= inv;
}

extern "C" void kernel_launch(void* const* d_in, const int* in_sizes, int n_in,
                              void* d_out, int out_size, void* d_ws, size_t ws_size,
                              hipStream_t stream) {
    const float* loss = (const float*)d_in[0];   // [N, 200]
    const float* Ws   = (const float*)d_in[1];   // [1, 200]
    const float* Wg   = (const float*)d_in[2];   // [1, 2]
    const int* esrc   = (const int*)d_in[3];     // [E]
    const int* edst   = (const int*)d_in[4];     // [E]
    float* out = (float*)d_out;                  // [N]

    const int n  = in_sizes[0] / 200;
    const int ne = in_sizes[3];
    const int Gh = (n + (NT / 16) - 1) / (NT / 16);

    const int nch = (n + CCH - 1) / CCH;                 // node chunks (6 @ n=100K)
    int split = 256 / nch; if (split < 1) split = 1;     // 1 block/CU, full residency
    const int epb = (((ne + split - 1) / split) + 15) & ~15;  // 16-aligned

    // ws layout (32-bit words):
    // h[n] | logit[n] (fallback only) | ordArr[n] | maxPart | sumPart |
    // partials[2*nch*split*CCH]
    float*    h        = (float*)d_ws;
    float*    logit    = h + n;
    unsigned* ordArr   = (unsigned*)(logit + n);
    float*    maxPart  = (float*)(ordArr + n);
    float*    sumPart  = maxPart + RED_BLOCKS;
    unsigned* partials = (unsigned*)(sumPart + RED_BLOCKS);
    size_t part_w = (size_t)2 * nch * split * CCH;
    size_t need = ((size_t)3 * n + 2 * RED_BLOCKS + part_w) * 4;

    k_h<<<Gh, NT, 0, stream>>>(loss, Ws, h, ordArr, n);

    if (need <= ws_size && n <= 2 * 256 * RED_BLOCKS) {
        k_accum<<<nch * split, AT, 0, stream>>>(esrc, edst, ordArr, partials, ne, nch, split, epb);
        k_fold_exp<<<RED_BLOCKS, 256, 0, stream>>>(h, partials, Wg, out, maxPart, sumPart, n, nch, split);
        k_norm2<<<RED_BLOCKS, 256, 0, stream>>>(maxPart, sumPart, out, n);
    } else if (need <= ws_size) {
        k_accum<<<nch * split, AT, 0, stream>>>(esrc, edst, ordArr, partials, ne, nch, split, epb);
        k_logit_max<<<RED_BLOCKS, 256, 0, stream>>>(h, partials, Wg, logit, maxPart, n, nch, split);
        k_exp_sum<<<RED_BLOCKS, 256, 0, stream>>>(logit, maxPart, out, sumPart, n);
        k_norm<<<RED_BLOCKS, 256, 0, stream>>>(sumPart, out, n);
    } else {
        hipMemsetAsync(partials, 0, (size_t)2 * (1 << 17) * 4, stream);
        k_edges_dev<<<(ne + 255) / 256, 256, 0, stream>>>(esrc, edst, h, partials, ne);
        k_logit_max_dev<<<RED_BLOCKS, 256, 0, stream>>>(h, partials, Wg, logit, maxPart, n);
        k_exp_sum<<<RED_BLOCKS, 256, 0, stream>>>(logit, maxPart, out, sumPart, n);
        k_norm<<<RED_BLOCKS, 256, 0, stream>>>(sumPart, out, n);
    }
}

// Round 22
// 72.112 us; speedup vs baseline: 1.0592x; 1.0592x over previous
//
#include <hip/hip_runtime.h>
#include <math.h>

#define RED_BLOCKS 256
#define NT 512             // k_h threads
#define AT 1024            // k_accum threads (16 waves, 1 block/CU)
#define CCH 16384          // nodes per chunk; both dirs = 128 KB LDS (r17 best: 46.5 us)
#define ORD_OFF 0x007fffffu  // f2ord(-inf); shifted so 0 == "-inf"/empty

// Monotone order-preserving float->uint mapping, shifted so 0 means -inf.
__device__ __forceinline__ unsigned f2ord(float f) {
    unsigned u = __float_as_uint(f);
    u = (u & 0x80000000u) ? ~u : (u | 0x80000000u);
    return u - ORD_OFF;
}
__device__ __forceinline__ float ord2f(unsigned uo) {
    unsigned u = uo + ORD_OFF;
    unsigned v = (u & 0x80000000u) ? (u & 0x7fffffffu) : ~u;
    return __uint_as_float(v);
}

__device__ __forceinline__ void h_row_body(const float* __restrict__ loss,
                                           const float* __restrict__ Ws,
                                           float* __restrict__ h,
                                           unsigned* __restrict__ ordArr,
                                           int n, int blk) {
    int sub = threadIdx.x & 15, r = threadIdx.x >> 4;   // 32 rows per 512-thread block
    int row = blk * (NT / 16) + r;
    if (row >= n) return;
    const float4* f4 = (const float4*)(loss + (size_t)row * 200);
    const float4* W4 = (const float4*)Ws;
    float4 a, w;
    float acc = 0.0f;
    a = f4[sub];      w = W4[sub];      acc += a.x*w.x + a.y*w.y + a.z*w.z + a.w*w.w;
    a = f4[sub + 16]; w = W4[sub + 16]; acc += a.x*w.x + a.y*w.y + a.z*w.z + a.w*w.w;
    a = f4[sub + 32]; w = W4[sub + 32]; acc += a.x*w.x + a.y*w.y + a.z*w.z + a.w*w.w;
    if (sub < 2) { a = f4[48 + sub]; w = W4[48 + sub]; acc += a.x*w.x + a.y*w.y + a.z*w.z + a.w*w.w; }
    #pragma unroll
    for (int off = 8; off > 0; off >>= 1) acc += __shfl_down(acc, off, 16);
    if (sub == 0) { h[row] = acc; ordArr[row] = f2ord(acc); }
}

__global__ void __launch_bounds__(NT) k_h(const float* __restrict__ loss,
                                          const float* __restrict__ Ws,
                                          float* __restrict__ h,
                                          unsigned* __restrict__ ordArr, int n) {
    h_row_body(loss, Ws, h, ordArr, n, blockIdx.x);
}

// Scatter-free segment-max (r17 config -- the measured optimum, 46.5 us).
// The edge phase is at the chip's random-access wall: 12.8M data-dependent
// lane-addresses (2/edge, forced: each direction moves a value between two
// random nodes) at ~2.2 cyc/CU each, invariant across 10 structural variants
// (atomics/scatter/gather, branchy/branchless, 6-10 passes, occupancy 37-75%).
// 3 phases per 16-edge pack: edge loads | exec-masked gathers | LDS atomics.
// Non-returning LDS atomics; exact, order-free -> bit-deterministic.
__global__ void __launch_bounds__(AT, 4) k_accum(
        const int* __restrict__ src, const int* __restrict__ dst,
        const unsigned* __restrict__ ordArr, unsigned* __restrict__ partials,
        int ne, int nch, int split, int epb) {
    __shared__ unsigned preL[CCH];
    __shared__ unsigned sucL[CCH];
    int c = blockIdx.x / split, sub = blockIdx.x - c * split;
    for (int t = threadIdx.x; t < CCH; t += AT) { preL[t] = 0u; sucL[t] = 0u; }
    __syncthreads();
    const unsigned clo = (unsigned)c * CCH;
    int lo = sub * epb, hi = min(sub * epb + epb, ne);

    int i = lo + (int)threadIdx.x * 16;
    for (; i + 15 < hi; i += AT * 16) {
        int4 s0 = *(const int4*)(src + i);
        int4 s1 = *(const int4*)(src + i + 4);
        int4 s2 = *(const int4*)(src + i + 8);
        int4 s3 = *(const int4*)(src + i + 12);
        int4 d0 = *(const int4*)(dst + i);
        int4 d1 = *(const int4*)(dst + i + 4);
        int4 d2 = *(const int4*)(dst + i + 8);
        int4 d3 = *(const int4*)(dst + i + 12);
        int ss[16] = { s0.x, s0.y, s0.z, s0.w, s1.x, s1.y, s1.z, s1.w,
                       s2.x, s2.y, s2.z, s2.w, s3.x, s3.y, s3.z, s3.w };
        int dd[16] = { d0.x, d0.y, d0.z, d0.w, d1.x, d1.y, d1.z, d1.w,
                       d2.x, d2.y, d2.z, d2.w, d3.x, d3.y, d3.z, d3.w };
        unsigned dl[16], sl[16], gp[16], gs[16];
        #pragma unroll
        for (int u = 0; u < 16; ++u) {
            bool same = (ss[u] == dd[u]);
            dl[u] = same ? ~0u : (unsigned)dd[u] - clo;
            sl[u] = same ? ~0u : (unsigned)ss[u] - clo;
            gp[u] = (dl[u] < CCH) ? ordArr[ss[u]] : 0u;
            gs[u] = (sl[u] < CCH) ? ordArr[dd[u]] : 0u;
        }
        #pragma unroll
        for (int u = 0; u < 16; ++u) {
            if (dl[u] < CCH) atomicMax(&preL[dl[u]], gp[u]);
            if (sl[u] < CCH) atomicMax(&sucL[sl[u]], gs[u]);
        }
    }
    for (int j = i; j < hi; ++j) {   // tail
        if (j >= lo) {
            int s = src[j], d = dst[j];
            if (s != d) {
                unsigned dl = (unsigned)d - clo;
                if (dl < CCH) atomicMax(&preL[dl], ordArr[s]);
                unsigned sl = (unsigned)s - clo;
                if (sl < CCH) atomicMax(&sucL[sl], ordArr[d]);
            }
        }
    }
    __syncthreads();
    size_t pb = ((size_t)c * split + sub) * CCH;
    size_t sucOff = (size_t)nch * split * CCH;
    for (int t = threadIdx.x; t < CCH; t += AT) {
        partials[pb + t] = preL[t];
        partials[sucOff + pb + t] = sucL[t];
    }
}

// Fused fold+logit+exp with BLOCK-LOCAL max; logits in named scalars
// (r19 lesson: runtime-indexed local arrays -> scratch -> 8x slowdown).
__global__ void __launch_bounds__(256) k_fold_exp(
        const float* __restrict__ h, const unsigned* __restrict__ partials,
        const float* __restrict__ Wg, float* __restrict__ out,
        float* __restrict__ maxPart, float* __restrict__ sumPart,
        int n, int nch, int split) {
    __shared__ float sm[256];
    float w0 = Wg[0], w1 = Wg[1];
    size_t sucOff = (size_t)nch * split * CCH;
    const int NTH = 256 * RED_BLOCKS;
    int i0 = blockIdx.x * 256 + threadIdx.x;
    int i1 = i0 + NTH;                         // n <= 2*65536 for this path

    float l0 = -INFINITY, l1 = -INFINITY;
    if (i0 < n) {
        int c = i0 / CCH, loc = i0 - c * CCH;
        const unsigned* pp = partials + ((size_t)c * split) * CCH + loc;
        const unsigned* sp = pp + sucOff;
        unsigned p = 0, s = 0;
        #pragma unroll 4
        for (int k = 0; k < split; ++k) {
            p = max(p, pp[(size_t)k * CCH]);
            s = max(s, sp[(size_t)k * CCH]);
        }
        l0 = h[i0] + w0 * (p ? ord2f(p) : 0.0f) + w1 * (s ? ord2f(s) : 0.0f);
    }
    if (i1 < n) {
        int c = i1 / CCH, loc = i1 - c * CCH;
        const unsigned* pp = partials + ((size_t)c * split) * CCH + loc;
        const unsigned* sp = pp + sucOff;
        unsigned p = 0, s = 0;
        #pragma unroll 4
        for (int k = 0; k < split; ++k) {
            p = max(p, pp[(size_t)k * CCH]);
            s = max(s, sp[(size_t)k * CCH]);
        }
        l1 = h[i1] + w0 * (p ? ord2f(p) : 0.0f) + w1 * (s ? ord2f(s) : 0.0f);
    }
    sm[threadIdx.x] = fmaxf(l0, l1);
    __syncthreads();
    for (int off = 128; off > 0; off >>= 1) {
        if (threadIdx.x < off) sm[threadIdx.x] = fmaxf(sm[threadIdx.x], sm[threadIdx.x + off]);
        __syncthreads();
    }
    float mb = sm[0];
    __syncthreads();
    float e0 = 0.0f, e1 = 0.0f;
    if (i0 < n) { e0 = expf(l0 - mb); out[i0] = e0; }
    if (i1 < n) { e1 = expf(l1 - mb); out[i1] = e1; }
    sm[threadIdx.x] = e0 + e1;
    __syncthreads();
    for (int off = 128; off > 0; off >>= 1) {
        if (threadIdx.x < off) sm[threadIdx.x] += sm[threadIdx.x + off];
        __syncthreads();
    }
    if (threadIdx.x == 0) { maxPart[blockIdx.x] = mb; sumPart[blockIdx.x] = sm[0]; }
}

// Every block redundantly (deterministically) computes gmax + rescaled sum,
// then rescales its own elements: out[i] *= exp(m_b - gmax) / S.
__global__ void __launch_bounds__(256) k_norm2(
        const float* __restrict__ maxPart, const float* __restrict__ sumPart,
        float* __restrict__ out, int n) {
    __shared__ float sm[256];
    const int NTH = 256 * RED_BLOCKS;
    sm[threadIdx.x] = maxPart[threadIdx.x];
    __syncthreads();
    for (int off = 128; off > 0; off >>= 1) {
        if (threadIdx.x < off) sm[threadIdx.x] = fmaxf(sm[threadIdx.x], sm[threadIdx.x + off]);
        __syncthreads();
    }
    float gmax = sm[0];
    __syncthreads();
    sm[threadIdx.x] = sumPart[threadIdx.x] * expf(maxPart[threadIdx.x] - gmax);
    __syncthreads();
    for (int off = 128; off > 0; off >>= 1) {
        if (threadIdx.x < off) sm[threadIdx.x] += sm[threadIdx.x + off];
        __syncthreads();
    }
    float scale = expf(maxPart[blockIdx.x] - gmax) / sm[0];
    int i0 = blockIdx.x * 256 + threadIdx.x;
    int i1 = i0 + NTH;
    if (i0 < n) out[i0] *= scale;
    if (i1 < n) out[i1] *= scale;
}

// ---- Fallback path (any n) ----
__global__ void k_edges_dev(const int* __restrict__ src, const int* __restrict__ dst,
                            const float* __restrict__ h, unsigned* __restrict__ partials, int ne) {
    int e = blockIdx.x * blockDim.x + threadIdx.x;
    if (e >= ne) return;
    int s = src[e], d = dst[e];
    if (s == d) return;
    unsigned hs = f2ord(h[s]);
    unsigned hd = f2ord(h[d]);
    unsigned* slot0 = &partials[d];
    unsigned* slot1 = &partials[(1 << 17) + s];
    if (*slot0 < hs) atomicMax(slot0, hs);
    if (*slot1 < hd) atomicMax(slot1, hd);
}

__global__ void k_logit_max(const float* __restrict__ h, const unsigned* __restrict__ partials,
                            const float* __restrict__ Wg, float* __restrict__ logit,
                            float* __restrict__ maxPart, int n, int nch, int split) {
    __shared__ float sm[256];
    float w0 = Wg[0], w1 = Wg[1];
    size_t sucOff = (size_t)nch * split * CCH;
    float m = -INFINITY;
    for (int i = blockIdx.x * 256 + threadIdx.x; i < n; i += 256 * RED_BLOCKS) {
        int c = i / CCH, loc = i - c * CCH;
        const unsigned* pp = partials + ((size_t)c * split) * CCH + loc;
        const unsigned* sp = pp + sucOff;
        unsigned p = 0, s = 0;
        #pragma unroll 4
        for (int k = 0; k < split; ++k) {
            p = max(p, pp[(size_t)k * CCH]);
            s = max(s, sp[(size_t)k * CCH]);
        }
        float pf = p ? ord2f(p) : 0.0f;
        float sf = s ? ord2f(s) : 0.0f;
        float l = h[i] + w0 * pf + w1 * sf;
        logit[i] = l;
        m = fmaxf(m, l);
    }
    sm[threadIdx.x] = m;
    __syncthreads();
    for (int off = 128; off > 0; off >>= 1) {
        if (threadIdx.x < off) sm[threadIdx.x] = fmaxf(sm[threadIdx.x], sm[threadIdx.x + off]);
        __syncthreads();
    }
    if (threadIdx.x == 0) maxPart[blockIdx.x] = sm[0];
}

__global__ void k_logit_max_dev(const float* __restrict__ h, const unsigned* __restrict__ partials,
                                const float* __restrict__ Wg, float* __restrict__ logit,
                                float* __restrict__ maxPart, int n) {
    __shared__ float sm[256];
    float w0 = Wg[0], w1 = Wg[1];
    float m = -INFINITY;
    for (int i = blockIdx.x * 256 + threadIdx.x; i < n; i += 256 * RED_BLOCKS) {
        unsigned p = partials[i], s = partials[(1 << 17) + i];
        float pf = p ? ord2f(p) : 0.0f;
        float sf = s ? ord2f(s) : 0.0f;
        float l = h[i] + w0 * pf + w1 * sf;
        logit[i] = l;
        m = fmaxf(m, l);
    }
    sm[threadIdx.x] = m;
    __syncthreads();
    for (int off = 128; off > 0; off >>= 1) {
        if (threadIdx.x < off) sm[threadIdx.x] = fmaxf(sm[threadIdx.x], sm[threadIdx.x + off]);
        __syncthreads();
    }
    if (threadIdx.x == 0) maxPart[blockIdx.x] = sm[0];
}

__global__ void k_exp_sum(const float* __restrict__ logit, const float* __restrict__ maxPart,
                          float* __restrict__ out, float* __restrict__ sumPart, int n) {
    __shared__ float sm[256];
    sm[threadIdx.x] = maxPart[threadIdx.x];
    __syncthreads();
    for (int off = 128; off > 0; off >>= 1) {
        if (threadIdx.x < off) sm[threadIdx.x] = fmaxf(sm[threadIdx.x], sm[threadIdx.x + off]);
        __syncthreads();
    }
    float gmax = sm[0];
    __syncthreads();
    float acc = 0.0f;
    for (int i = blockIdx.x * 256 + threadIdx.x; i < n; i += 256 * RED_BLOCKS) {
        float e = expf(logit[i] - gmax);
        out[i] = e;
        acc += e;
    }
    sm[threadIdx.x] = acc;
    __syncthreads();
    for (int off = 128; off > 0; off >>= 1) {
        if (threadIdx.x < off) sm[threadIdx.x] += sm[threadIdx.x + off];
        __syncthreads();
    }
    if (threadIdx.x == 0) sumPart[blockIdx.x] = sm[0];
}

__global__ void k_norm(const float* __restrict__ sumPart, float* __restrict__ out, int n) {
    __shared__ float sm[256];
    sm[threadIdx.x] = sumPart[threadIdx.x];
    __syncthreads();
    for (int off = 128; off > 0; off >>= 1) {
        if (threadIdx.x < off) sm[threadIdx.x] += sm[threadIdx.x + off];
        __syncthreads();
    }
    float inv = 1.0f / sm[0];
    for (int i = blockIdx.x * 256 + threadIdx.x; i < n; i += 256 * RED_BLOCKS) out[i] *= inv;
}

extern "C" void kernel_launch(void* const* d_in, const int* in_sizes, int n_in,
                              void* d_out, int out_size, void* d_ws, size_t ws_size,
                              hipStream_t stream) {
    const float* loss = (const float*)d_in[0];   // [N, 200]
    const float* Ws   = (const float*)d_in[1];   // [1, 200]
    const float* Wg   = (const float*)d_in[2];   // [1, 2]
    const int* esrc   = (const int*)d_in[3];     // [E]
    const int* edst   = (const int*)d_in[4];     // [E]
    float* out = (float*)d_out;                  // [N]

    const int n  = in_sizes[0] / 200;
    const int ne = in_sizes[3];
    const int Gh = (n + (NT / 16) - 1) / (NT / 16);

    const int nch = (n + CCH - 1) / CCH;                 // node chunks (7 @ n=100K)
    int split = 256 / nch; if (split < 1) split = 1;     // 1 block/CU, full residency
    const int epb = (((ne + split - 1) / split) + 15) & ~15;  // 16-aligned

    // ws layout (32-bit words):
    // h[n] | logit[n] (fallback only) | ordArr[n] | maxPart | sumPart |
    // partials[2*nch*split*CCH]
    float*    h        = (float*)d_ws;
    float*    logit    = h + n;
    unsigned* ordArr   = (unsigned*)(logit + n);
    float*    maxPart  = (float*)(ordArr + n);
    float*    sumPart  = maxPart + RED_BLOCKS;
    unsigned* partials = (unsigned*)(sumPart + RED_BLOCKS);
    size_t part_w = (size_t)2 * nch * split * CCH;
    size_t need = ((size_t)3 * n + 2 * RED_BLOCKS + part_w) * 4;

    k_h<<<Gh, NT, 0, stream>>>(loss, Ws, h, ordArr, n);

    if (need <= ws_size && n <= 2 * 256 * RED_BLOCKS) {
        k_accum<<<nch * split, AT, 0, stream>>>(esrc, edst, ordArr, partials, ne, nch, split, epb);
        k_fold_exp<<<RED_BLOCKS, 256, 0, stream>>>(h, partials, Wg, out, maxPart, sumPart, n, nch, split);
        k_norm2<<<RED_BLOCKS, 256, 0, stream>>>(maxPart, sumPart, out, n);
    } else if (need <= ws_size) {
        k_accum<<<nch * split, AT, 0, stream>>>(esrc, edst, ordArr, partials, ne, nch, split, epb);
        k_logit_max<<<RED_BLOCKS, 256, 0, stream>>>(h, partials, Wg, logit, maxPart, n, nch, split);
        k_exp_sum<<<RED_BLOCKS, 256, 0, stream>>>(logit, maxPart, out, sumPart, n);
        k_norm<<<RED_BLOCKS, 256, 0, stream>>>(sumPart, out, n);
    } else {
        hipMemsetAsync(partials, 0, (size_t)2 * (1 << 17) * 4, stream);
        k_edges_dev<<<(ne + 255) / 256, 256, 0, stream>>>(esrc, edst, h, partials, ne);
        k_logit_max_dev<<<RED_BLOCKS, 256, 0, stream>>>(h, partials, Wg, logit, maxPart, n);
        k_exp_sum<<<RED_BLOCKS, 256, 0, stream>>>(logit, maxPart, out, sumPart, n);
        k_norm<<<RED_BLOCKS, 256, 0, stream>>>(sumPart, out, n);
    }
}